// Round 3
// baseline (55.314 us; speedup 1.0000x reference)
//
#include <hip/hip_runtime.h>
#include <math.h>

#define CUTOFF2 100.0f
#define EW_ALPHA 0.3f
#define NBLOCKS 2048
#define NTHREADS 256
#define N_ATOMS_MAX_PAD 16  // floats per packed atom record (64 B)

__global__ __launch_bounds__(256)
void pack_atoms_kernel(const float* __restrict__ coords,
                       const float* __restrict__ q,
                       const float* __restrict__ p,
                       const float* __restrict__ t,
                       float* __restrict__ packed,
                       int n_atoms) {
    int i = blockIdx.x * blockDim.x + threadIdx.x;
    if (i >= n_atoms) return;
    const float* ti = t + 9*i;
    float4 a0 = make_float4(coords[3*i+0], coords[3*i+1], coords[3*i+2], q[i]);
    float4 a1 = make_float4(p[3*i+0], p[3*i+1], p[3*i+2], ti[0] * (1.0f/3.0f));
    float4 a2 = make_float4((ti[1] + ti[3]) * (1.0f/3.0f),
                            (ti[2] + ti[6]) * (1.0f/3.0f),
                            ti[4] * (1.0f/3.0f),
                            (ti[5] + ti[7]) * (1.0f/3.0f));
    float4 a3 = make_float4(ti[8] * (1.0f/3.0f), 0.0f, 0.0f, 0.0f);
    float4* dst = reinterpret_cast<float4*>(packed + 16*i);
    dst[0] = a0; dst[1] = a1; dst[2] = a2; dst[3] = a3;
}

__global__ __launch_bounds__(NTHREADS)
void mp_pair_energy_kernel(const float* __restrict__ packed,
                           const float* __restrict__ box,
                           const long long* __restrict__ pairs,
                           double* __restrict__ partial,
                           int n_pairs) {
    const float Lx = box[0], Ly = box[4], Lz = box[8];
    const float iLx = 1.0f / Lx, iLy = 1.0f / Ly, iLz = 1.0f / Lz;
    const float PREF = 1.1283791670955126f; // 2/sqrt(pi)

    double acc = 0.0;
    const int stride = gridDim.x * blockDim.x;
    for (int idx = blockIdx.x * blockDim.x + threadIdx.x; idx < n_pairs; idx += stride) {
        // nontemporal: don't let the 16MB pairs stream evict the atom table from L2
        long long v = __builtin_nontemporal_load(pairs + idx);
        int i = (int)(v & 0xffffffffLL);        // pairs[:,0] -> mi
        int j = (int)(v >> 32);                 // pairs[:,1] -> mj

        const float4* Ai = reinterpret_cast<const float4*>(packed + 16*i);
        const float4* Aj = reinterpret_cast<const float4*>(packed + 16*j);
        float4 i0 = Ai[0], i1 = Ai[1], i2 = Ai[2];
        float  mi9 = packed[16*i + 12];
        float4 j0 = Aj[0], j1 = Aj[1], j2 = Aj[2];
        float  mj9 = packed[16*j + 12];

        float dx = j0.x - i0.x;
        float dy = j0.y - i0.y;
        float dz = j0.z - i0.z;
        float x = dx - rintf(dx * iLx) * Lx;
        float y = dy - rintf(dy * iLy) * Ly;
        float z = dz - rintf(dz * iLz) * Lz;

        float r2 = x*x + y*y + z*z;
        if (r2 > CUTOFF2) continue;

        float r = sqrtf(r2);
        float rinv = 1.0f / r;

        float u  = EW_ALPHA * r;
        float u2 = u*u;
        float u3 = u2*u, u5 = u3*u2, u7 = u5*u2;
        float e2 = expf(-u2);
        float ec = erfcf(u);
        float d1 = ec;
        float d3 = ec + PREF * u * e2;
        float d5 = ec + PREF * ((3.0f*u + 2.0f*u3) * (1.0f/3.0f)) * e2;
        float d7 = ec + PREF * ((15.0f*u + 10.0f*u3 + 4.0f*u5) * (1.0f/15.0f)) * e2;
        float d9 = ec + PREF * ((105.0f*u + 70.0f*u3 + 28.0f*u5 + 8.0f*u7) * (1.0f/105.0f)) * e2;

        float ri2 = rinv * rinv;
        float r3i = rinv * ri2;
        float r5i = r3i * ri2;
        float r7i = r5i * ri2;
        float r9i = r7i * ri2;
        float R1 = rinv * d1;
        float R3 = r3i * d3;
        float R5 = r5i * d5;
        float R7 = r7i * d7;
        float R9 = r9i * d9;

        float x2 = x*x, y2 = y*y, z2 = z*z;
        float xy = x*y, xz = x*z, yz = y*z;

        float tx = -x * R3, ty = -y * R3, tz = -z * R3;
        float txx = 3.0f*x2*R5 - R3;
        float txy = 3.0f*xy*R5;
        float txz = 3.0f*xz*R5;
        float tyy = 3.0f*y2*R5 - R3;
        float tyz = 3.0f*yz*R5;
        float tzz = 3.0f*z2*R5 - R3;
        float txxx = x*(9.0f*R5 - 15.0f*x2*R7);
        float txxy = y*(3.0f*R5 - 15.0f*x2*R7);
        float txxz = z*(3.0f*R5 - 15.0f*x2*R7);
        float tyyy = y*(9.0f*R5 - 15.0f*y2*R7);
        float tyyx = x*(3.0f*R5 - 15.0f*y2*R7);
        float tyyz = z*(3.0f*R5 - 15.0f*y2*R7);
        float tzzz = z*(9.0f*R5 - 15.0f*z2*R7);
        float tzzx = x*(3.0f*R5 - 15.0f*z2*R7);
        float tzzy = y*(3.0f*R5 - 15.0f*z2*R7);
        float txyz = -15.0f*x*yz*R7;
        float txxxx = 105.0f*x2*x2*R9 - 90.0f*x2*R7 + 9.0f*R5;
        float txxxy = xy*(105.0f*x2*R9 - 45.0f*R7);
        float txxxz = xz*(105.0f*x2*R9 - 45.0f*R7);
        float txxyy = 105.0f*x2*y2*R9 - 15.0f*(x2+y2)*R7 + 3.0f*R5;
        float txxzz = 105.0f*x2*z2*R9 - 15.0f*(x2+z2)*R7 + 3.0f*R5;
        float txxyz = yz*(105.0f*x2*R9 - 15.0f*R7);
        float tyyyy = 105.0f*y2*y2*R9 - 90.0f*y2*R7 + 9.0f*R5;
        float tyyyx = xy*(105.0f*y2*R9 - 45.0f*R7);
        float tyyyz = yz*(105.0f*y2*R9 - 45.0f*R7);
        float tyyzz = 105.0f*y2*z2*R9 - 15.0f*(y2+z2)*R7 + 3.0f*R5;
        float tyyxz = xz*(105.0f*y2*R9 - 15.0f*R7);
        float tzzzz = 105.0f*z2*z2*R9 - 90.0f*z2*R7 + 9.0f*R5;
        float tzzzx = xz*(105.0f*z2*R9 - 45.0f*R7);
        float tzzzy = yz*(105.0f*z2*R9 - 45.0f*R7);
        float tzzxy = xy*(105.0f*z2*R9 - 15.0f*R7);

        float mi0 = i0.w;
        float mi1 = i1.x, mi2 = i1.y, mi3 = i1.z;
        float mi4 = i1.w;
        float mi5 = i2.x, mi6 = i2.y, mi7 = i2.z, mi8 = i2.w;
        float mj0 = j0.w;
        float mj1 = j1.x, mj2 = j1.y, mj3 = j1.z;
        float mj4 = j1.w;
        float mj5 = j2.x, mj6 = j2.y, mj7 = j2.z, mj8 = j2.w;

        float E0 = R1*mi0  - tx*mi1   - ty*mi2   - tz*mi3   + txx*mi4   + txy*mi5   + txz*mi6   + tyy*mi7   + tyz*mi8   + tzz*mi9;
        float E1 = tx*mi0  - txx*mi1  - txy*mi2  - txz*mi3  + txxx*mi4  + txxy*mi5  + txxz*mi6  + tyyx*mi7  + txyz*mi8  + tzzx*mi9;
        float E2 = ty*mi0  - txy*mi1  - tyy*mi2  - tyz*mi3  + txxy*mi4  + tyyx*mi5  + txyz*mi6  + tyyy*mi7  + tyyz*mi8  + tzzy*mi9;
        float E3 = tz*mi0  - txz*mi1  - tyz*mi2  - tzz*mi3  + txxz*mi4  + txyz*mi5  + tzzx*mi6  + tyyz*mi7  + tzzy*mi8  + tzzz*mi9;
        float E4 = txx*mi0 - txxx*mi1 - txxy*mi2 - txxz*mi3 + txxxx*mi4 + txxxy*mi5 + txxxz*mi6 + txxyy*mi7 + txxyz*mi8 + txxzz*mi9;
        float E5 = txy*mi0 - txxy*mi1 - tyyx*mi2 - txyz*mi3 + txxxy*mi4 + txxyy*mi5 + txxyz*mi6 + tyyyx*mi7 + tyyxz*mi8 + tzzxy*mi9;
        float E6 = txz*mi0 - txxz*mi1 - txyz*mi2 - tzzx*mi3 + txxxz*mi4 + txxyz*mi5 + txxzz*mi6 + tyyxz*mi7 + tzzxy*mi8 + tzzzx*mi9;
        float E7 = tyy*mi0 - tyyx*mi1 - tyyy*mi2 - tyyz*mi3 + txxyy*mi4 + tyyyx*mi5 + tyyxz*mi6 + tyyyy*mi7 + tyyyz*mi8 + tyyzz*mi9;
        float E8 = tyz*mi0 - txyz*mi1 - tyyz*mi2 - tzzy*mi3 + txxyz*mi4 + tyyxz*mi5 + tzzxy*mi6 + tyyyz*mi7 + tyyzz*mi8 + tzzzy*mi9;
        float E9 = tzz*mi0 - tzzx*mi1 - tzzy*mi2 - tzzz*mi3 + txxzz*mi4 + tzzxy*mi5 + tzzzx*mi6 + tyyzz*mi7 + tzzzy*mi8 + tzzzz*mi9;

        float e = mj0*E0 + mj1*E1 + mj2*E2 + mj3*E3 + mj4*E4
                + mj5*E5 + mj6*E6 + mj7*E7 + mj8*E8 + mj9*E9;

        acc += (double)e;
    }

    __shared__ double sdata[NTHREADS];
    int tid = threadIdx.x;
    sdata[tid] = acc;
    __syncthreads();
    for (int s = NTHREADS/2; s > 0; s >>= 1) {
        if (tid < s) sdata[tid] += sdata[tid + s];
        __syncthreads();
    }
    if (tid == 0) partial[blockIdx.x] = sdata[0];
}

__global__ __launch_bounds__(256)
void mp_reduce_kernel(const double* __restrict__ partial, int n, float* __restrict__ out) {
    __shared__ double sdata[256];
    int tid = threadIdx.x;
    double a = 0.0;
    for (int i = tid; i < n; i += 256) a += partial[i];
    sdata[tid] = a;
    __syncthreads();
    for (int s = 128; s > 0; s >>= 1) {
        if (tid < s) sdata[tid] += sdata[tid + s];
        __syncthreads();
    }
    if (tid == 0) out[0] = (float)sdata[0];
}

extern "C" void kernel_launch(void* const* d_in, const int* in_sizes, int n_in,
                              void* d_out, int out_size, void* d_ws, size_t ws_size,
                              hipStream_t stream) {
    const float* coords = (const float*)d_in[0];
    const float* box    = (const float*)d_in[1];
    const int*   pairs  = (const int*)d_in[2];
    const float* q      = (const float*)d_in[3];
    const float* p      = (const float*)d_in[4];
    const float* t      = (const float*)d_in[5];
    int n_pairs = in_sizes[2] / 2;
    int n_atoms = in_sizes[3];

    // ws layout: [packed atoms: n_atoms*64B] [partials: NBLOCKS*8B]
    size_t packed_bytes = (size_t)n_atoms * 16 * sizeof(float);
    float*  packed  = (float*)d_ws;
    double* partial = (double*)((char*)d_ws + ((packed_bytes + 255) & ~(size_t)255));

    pack_atoms_kernel<<<(n_atoms + 255) / 256, 256, 0, stream>>>(
        coords, q, p, t, packed, n_atoms);
    mp_pair_energy_kernel<<<NBLOCKS, NTHREADS, 0, stream>>>(
        packed, box, (const long long*)pairs, partial, n_pairs);
    mp_reduce_kernel<<<1, 256, 0, stream>>>(partial, NBLOCKS, (float*)d_out);
}